// Round 7
// baseline (1937.633 us; speedup 1.0000x reference)
//
#include <hip/hip_runtime.h>
#include <math.h>

#define N_TOK 64
#define DIM   256
#define HEADS 8
#define HDIM  32
#define FFN   1024
#define EPSV  1e-5f

// LDS strides (in elements). All give 16B-aligned rows.
#define SB    264   // bf16 [64][256] buffers (XHB / QB / KB / OB / XHB2)
#define VTS   72    // V^T bf16 [256][64]
#define PST   72    // P bf16 [64][64]
#define SSF   68    // S fp32 [64][64]
#define HBS   136   // gelu chunk bf16 [64][128]
#define X1S   260   // x1 fp32 [64][256]

typedef __attribute__((ext_vector_type(8))) short  short8;  // 8 bf16 = 4 VGPR
typedef __attribute__((ext_vector_type(4))) float  f32x4;

__device__ __forceinline__ f32x4 MFMA(short8 a, short8 b, f32x4 c) {
    return __builtin_amdgcn_mfma_f32_16x16x32_bf16(a, b, c, 0, 0, 0);
}

__device__ __forceinline__ unsigned short f2bf(float f) {
    union { float f; unsigned u; } v; v.f = f;
    unsigned r = (v.u + 0x7FFFu + ((v.u >> 16) & 1u)) >> 16;   // RNE
    return (unsigned short)r;
}

__device__ __forceinline__ short8 pack8(const float4& a, const float4& b) {
    short8 r;
    r[0] = (short)f2bf(a.x); r[1] = (short)f2bf(a.y);
    r[2] = (short)f2bf(a.z); r[3] = (short)f2bf(a.w);
    r[4] = (short)f2bf(b.x); r[5] = (short)f2bf(b.y);
    r[6] = (short)f2bf(b.z); r[7] = (short)f2bf(b.w);
    return r;
}

__device__ __forceinline__ float gelu_exact(float u) {
    return 0.5f * u * (1.0f + erff(u * 0.70710678118654752f));
}

// ---------------------------------------------------------------------------
// Fold + bf16-convert weights; pre-gather dense attention bias.
// ---------------------------------------------------------------------------
__global__ __launch_bounds__(256) void swin_fold(
    const float* __restrict__ qkv_w, const float* __restrict__ qkv_b,
    const float* __restrict__ n1_w,  const float* __restrict__ n1_b,
    const float* __restrict__ fc1_w, const float* __restrict__ fc1_b,
    const float* __restrict__ n2_w,  const float* __restrict__ n2_b,
    const float* __restrict__ proj_w, const float* __restrict__ fc2_w,
    const float* __restrict__ bias_table, const int* __restrict__ rel_index,
    unsigned short* __restrict__ wqkv_bf, float* __restrict__ bqkv,
    unsigned short* __restrict__ wfc1_bf, float* __restrict__ bfc1,
    unsigned short* __restrict__ wproj_bf, unsigned short* __restrict__ wfc2_bf,
    float* __restrict__ BT)
{
    const int blk = blockIdx.x;
    const int t   = threadIdx.x;
    __shared__ float red[4];
    if (blk < 768) {
        const int r = blk;
        const float scale = (r < DIM) ? 0.17677669529663687f : 1.0f;
        const float w = qkv_w[r * DIM + t];
        wqkv_bf[r * DIM + t] = f2bf(w * n1_w[t] * scale);
        float p = w * n1_b[t];
#pragma unroll
        for (int m = 1; m < 64; m <<= 1) p += __shfl_xor(p, m);
        if ((t & 63) == 0) red[t >> 6] = p;
        __syncthreads();
        if (t == 0) bqkv[r] = (qkv_b[r] + red[0] + red[1] + red[2] + red[3]) * scale;
    } else if (blk < 1792) {
        const int q = blk - 768;
        const float w = fc1_w[q * DIM + t];
        wfc1_bf[q * DIM + t] = f2bf(w * n2_w[t]);
        float p = w * n2_b[t];
#pragma unroll
        for (int m = 1; m < 64; m <<= 1) p += __shfl_xor(p, m);
        if ((t & 63) == 0) red[t >> 6] = p;
        __syncthreads();
        if (t == 0) bfc1[q] = fc1_b[q] + red[0] + red[1] + red[2] + red[3];
    } else if (blk < 2048) {
        const int r = blk - 1792;
        wproj_bf[r * DIM + t] = f2bf(proj_w[r * DIM + t]);
    } else if (blk < 2304) {
        const int r = blk - 2048;
#pragma unroll
        for (int i = 0; i < 4; ++i) {
            const int c = t + i * 256;
            wfc2_bf[r * FFN + c] = f2bf(fc2_w[r * FFN + c]);
        }
    } else {
        const int idx = (blk - 2304) * 256 + t;          // [0, 32768)
        const int h = idx >> 12, rc = idx & 4095;
        BT[idx] = bias_table[rel_index[rc] * HEADS + h];
    }
}

// ---------------------------------------------------------------------------
// Fused Swin block, all GEMMs on MFMA. 1 block (512 thr, 8 waves) / window.
// Fragment layouts (v_mfma_f32_16x16x32_bf16):
//   A: lane holds A[row=l&15][k=(l>>4)*8+i], i=0..7      (contiguous bf16x8)
//   B: lane holds B[k=(l>>4)*8+i][col=l&15]
//   D: lane holds D[row=(l>>4)*4+j][col=l&15], j=0..3    (HW-verified m89)
// ---------------------------------------------------------------------------
__global__ __launch_bounds__(512, 2) void swin_block(
    const float* __restrict__ x,
    const unsigned short* __restrict__ wqkv, const float* __restrict__ bqkv,
    const unsigned short* __restrict__ wproj, const float* __restrict__ proj_b,
    const float* __restrict__ BT,
    const unsigned short* __restrict__ wfc1, const float* __restrict__ bfc1,
    const unsigned short* __restrict__ wfc2, const float* __restrict__ fc2_b,
    float* __restrict__ out)
{
    // LDS: R1 [0,33792) | R2 [33792,138240) | R3 [138240,155648)
    __shared__ __align__(16) unsigned char smem[155648];
    unsigned short* const XHB = (unsigned short*)smem;              // [64][SB] x_hat -> O -> x1_hat
    unsigned short* const QB  = (unsigned short*)(smem + 33792);    // [64][SB]
    unsigned short* const KB  = (unsigned short*)(smem + 67584);    // [64][SB]
    unsigned short* const VT  = (unsigned short*)(smem + 101376);   // [256][VTS]  (V transposed)
    float*          const X1  = (float*)(smem + 33792);             // [64][X1S], aliases QB/KB/VT
    float*          const SS  = (float*)(smem + 138240);            // [64][SSF]
    unsigned short* const PB  = (unsigned short*)(smem + 138240);   // [64][PST], aliases SS
    unsigned short* const HB  = (unsigned short*)(smem + 138240);   // [64][HBS], aliases SS

    const int b    = blockIdx.x;
    const int tid  = threadIdx.x;
    const int w    = tid >> 6;        // wave 0..7
    const int lane = tid & 63;
    const int lr   = lane & 15;       // fragment row/col
    const int kg   = lane >> 4;       // fragment k-group
    const float* __restrict__ xb = x + (size_t)b * (N_TOK * DIM);

    // ---- Phase 0: LN1 -> XHB (bf16) ----
    {
        const int r = tid >> 3, p = tid & 7;
        const int c0 = p * 32;
        float4 v[8];
        float s = 0.f, s2 = 0.f;
#pragma unroll
        for (int i = 0; i < 8; ++i) {
            v[i] = *(const float4*)(xb + r * DIM + c0 + 4 * i);
            s  += v[i].x + v[i].y + v[i].z + v[i].w;
            s2 += v[i].x * v[i].x + v[i].y * v[i].y + v[i].z * v[i].z + v[i].w * v[i].w;
        }
#pragma unroll
        for (int m = 1; m < 8; m <<= 1) { s += __shfl_xor(s, m); s2 += __shfl_xor(s2, m); }
        const float mu  = s * (1.f / 256.f);
        const float var = fmaxf(s2 * (1.f / 256.f) - mu * mu, 0.f);
        const float rs  = rsqrtf(var + EPSV);
#pragma unroll
        for (int i = 0; i < 8; i += 2) {
            float4 h0, h1;
            h0.x = (v[i].x - mu) * rs;   h0.y = (v[i].y - mu) * rs;
            h0.z = (v[i].z - mu) * rs;   h0.w = (v[i].w - mu) * rs;
            h1.x = (v[i+1].x - mu) * rs; h1.y = (v[i+1].y - mu) * rs;
            h1.z = (v[i+1].z - mu) * rs; h1.w = (v[i+1].w - mu) * rs;
            *(short8*)&XHB[r * SB + c0 + 4 * i] = pack8(h0, h1);
        }
    }
    __syncthreads();

    // ---- Phase 1: qkv GEMM (64x256 @ 256x768) -> QB, KB, VT ----
    {
        const int r0 = (w & 3) * 16;
        const int cb = (w >> 2) * 384;
        f32x4 acc[24];
#pragma unroll
        for (int ct = 0; ct < 24; ++ct) {
            const float bb = bqkv[cb + ct * 16 + lr];
            acc[ct] = (f32x4){bb, bb, bb, bb};
        }
#pragma unroll 1
        for (int ks = 0; ks < 8; ++ks) {
            const int kb = ks * 32;
            const short8 a = *(const short8*)&XHB[(r0 + lr) * SB + kb + kg * 8];
#pragma unroll
            for (int ct = 0; ct < 24; ++ct) {
                const int o = cb + ct * 16 + lr;
                const short8 bf = *(const short8*)&wqkv[(size_t)o * DIM + kb + kg * 8];
                acc[ct] = MFMA(a, bf, acc[ct]);
            }
        }
#pragma unroll
        for (int ct = 0; ct < 24; ++ct) {
            const int o = cb + ct * 16 + lr;
#pragma unroll
            for (int j = 0; j < 4; ++j) {
                const int grow = r0 + (kg << 2) + j;
                const unsigned short bv = f2bf(acc[ct][j]);
                if (o < 256)      QB[grow * SB + o] = bv;
                else if (o < 512) KB[grow * SB + (o - 256)] = bv;
                else              VT[(o - 512) * VTS + grow] = bv;
            }
        }
    }
    __syncthreads();

    // ---- Phase 2: attention, per head ----
    for (int hd = 0; hd < HEADS; ++hd) {
        // [a] S = Q.K^T + bias -> SS (fp32). Wave: rows (w>>1)*16, col pair (w&1)*2.
        {
            const int rt = w >> 1, cp = w & 1;
            const short8 aq = *(const short8*)&QB[(rt * 16 + lr) * SB + hd * HDIM + kg * 8];
#pragma unroll
            for (int cc = 0; cc < 2; ++cc) {
                const int ctt = cp * 2 + cc;
                const short8 bk = *(const short8*)&KB[(ctt * 16 + lr) * SB + hd * HDIM + kg * 8];
                f32x4 sacc = (f32x4){0.f, 0.f, 0.f, 0.f};
                sacc = MFMA(aq, bk, sacc);
#pragma unroll
                for (int j = 0; j < 4; ++j) {
                    const int grow = rt * 16 + (kg << 2) + j;
                    const int gcol = ctt * 16 + lr;
                    SS[grow * SSF + gcol] = sacc[j] + BT[hd * 4096 + grow * 64 + gcol];
                }
            }
        }
        __syncthreads();
        // [b1] row softmax in registers (8 lanes per row)
        float4 f0, f1;
        {
            const int r = tid >> 3, p = tid & 7;
            const int j0 = p * 8;
            f0 = *(const float4*)&SS[r * SSF + j0];
            f1 = *(const float4*)&SS[r * SSF + j0 + 4];
            float m = fmaxf(fmaxf(fmaxf(f0.x, f0.y), fmaxf(f0.z, f0.w)),
                            fmaxf(fmaxf(f1.x, f1.y), fmaxf(f1.z, f1.w)));
#pragma unroll
            for (int msk = 1; msk < 8; msk <<= 1) m = fmaxf(m, __shfl_xor(m, msk));
            f0.x = __expf(f0.x - m); f0.y = __expf(f0.y - m);
            f0.z = __expf(f0.z - m); f0.w = __expf(f0.w - m);
            f1.x = __expf(f1.x - m); f1.y = __expf(f1.y - m);
            f1.z = __expf(f1.z - m); f1.w = __expf(f1.w - m);
            float sum = f0.x + f0.y + f0.z + f0.w + f1.x + f1.y + f1.z + f1.w;
#pragma unroll
            for (int msk = 1; msk < 8; msk <<= 1) sum += __shfl_xor(sum, msk);
            const float inv = 1.f / sum;
            f0.x *= inv; f0.y *= inv; f0.z *= inv; f0.w *= inv;
            f1.x *= inv; f1.y *= inv; f1.z *= inv; f1.w *= inv;
        }
        __syncthreads();   // all SS reads done; PB may overwrite the region
        // [b2] write probs bf16 -> PB
        {
            const int r = tid >> 3, p = tid & 7;
            *(short8*)&PB[r * PST + p * 8] = pack8(f0, f1);
        }
        __syncthreads();
        // [c] O = P @ V -> OB (=XHB) cols hd*32..  Wave: rows (w>>1)*16, col tile w&1.
        {
            const int rt = w >> 1, ctp = w & 1;
            f32x4 oacc = (f32x4){0.f, 0.f, 0.f, 0.f};
#pragma unroll
            for (int ks = 0; ks < 2; ++ks) {
                const int kb = ks * 32;
                const short8 ap = *(const short8*)&PB[(rt * 16 + lr) * PST + kb + kg * 8];
                const short8 bv = *(const short8*)&VT[(hd * HDIM + ctp * 16 + lr) * VTS + kb + kg * 8];
                oacc = MFMA(ap, bv, oacc);
            }
#pragma unroll
            for (int j = 0; j < 4; ++j) {
                const int grow = rt * 16 + (kg << 2) + j;
                XHB[grow * SB + hd * HDIM + ctp * 16 + lr] = f2bf(oacc[j]);
            }
        }
        __syncthreads();   // [c] PB/VT reads done before next [a] writes SS
    }

    // ---- Phase 3: proj + residual -> X1 (fp32, aliases QB/KB/VT) ----
    {
        const int r0 = (w & 3) * 16;
        const int cgrp = w >> 2;
        f32x4 acc[8];
#pragma unroll
        for (int ct = 0; ct < 8; ++ct) {
            const float bb = proj_b[cgrp * 128 + ct * 16 + lr];
            acc[ct] = (f32x4){bb, bb, bb, bb};
        }
#pragma unroll 1
        for (int ks = 0; ks < 8; ++ks) {
            const int kb = ks * 32;
            const short8 a = *(const short8*)&XHB[(r0 + lr) * SB + kb + kg * 8];
#pragma unroll
            for (int ct = 0; ct < 8; ++ct) {
                const int o = cgrp * 128 + ct * 16 + lr;
                const short8 bf = *(const short8*)&wproj[(size_t)o * DIM + kb + kg * 8];
                acc[ct] = MFMA(a, bf, acc[ct]);
            }
        }
#pragma unroll
        for (int ct = 0; ct < 8; ++ct) {
            const int col = cgrp * 128 + ct * 16 + lr;
#pragma unroll
            for (int j = 0; j < 4; ++j) {
                const int grow = r0 + (kg << 2) + j;
                X1[grow * X1S + col] = acc[ct][j] + xb[grow * DIM + col];
            }
        }
    }
    __syncthreads();

    // ---- LN2: X1 -> XHB (x1_hat bf16; O dead) ----
    {
        const int r = tid >> 3, p = tid & 7;
        const int c0 = p * 32;
        float4 v[8];
        float s = 0.f, s2 = 0.f;
#pragma unroll
        for (int i = 0; i < 8; ++i) {
            v[i] = *(const float4*)&X1[r * X1S + c0 + 4 * i];
            s  += v[i].x + v[i].y + v[i].z + v[i].w;
            s2 += v[i].x * v[i].x + v[i].y * v[i].y + v[i].z * v[i].z + v[i].w * v[i].w;
        }
#pragma unroll
        for (int m = 1; m < 8; m <<= 1) { s += __shfl_xor(s, m); s2 += __shfl_xor(s2, m); }
        const float mu  = s * (1.f / 256.f);
        const float var = fmaxf(s2 * (1.f / 256.f) - mu * mu, 0.f);
        const float rs  = rsqrtf(var + EPSV);
#pragma unroll
        for (int i = 0; i < 8; i += 2) {
            float4 h0, h1;
            h0.x = (v[i].x - mu) * rs;   h0.y = (v[i].y - mu) * rs;
            h0.z = (v[i].z - mu) * rs;   h0.w = (v[i].w - mu) * rs;
            h1.x = (v[i+1].x - mu) * rs; h1.y = (v[i+1].y - mu) * rs;
            h1.z = (v[i+1].z - mu) * rs; h1.w = (v[i+1].w - mu) * rs;
            *(short8*)&XHB[r * SB + c0 + 4 * i] = pack8(h0, h1);
        }
    }
    __syncthreads();

    // ---- Phase 4: MLP, hidden in 8 chunks of 128 through HB ----
    const int r0m  = (w & 3) * 16;
    const int chal = w >> 2;
    f32x4 acc2[8];
#pragma unroll
    for (int ct = 0; ct < 8; ++ct) {
        const float bb = fc2_b[chal * 128 + ct * 16 + lr];
        acc2[ct] = (f32x4){bb, bb, bb, bb};
    }
    for (int ch = 0; ch < 8; ++ch) {
        // fc1 chunk + gelu -> HB
        {
            f32x4 acc1[4];
#pragma unroll
            for (int cf = 0; cf < 4; ++cf) {
                const int hl = chal * 64 + cf * 16 + lr;
                const float bb = bfc1[ch * 128 + hl];
                acc1[cf] = (f32x4){bb, bb, bb, bb};
            }
#pragma unroll 1
            for (int ks = 0; ks < 8; ++ks) {
                const int kb = ks * 32;
                const short8 a = *(const short8*)&XHB[(r0m + lr) * SB + kb + kg * 8];
#pragma unroll
                for (int cf = 0; cf < 4; ++cf) {
                    const int hcol = ch * 128 + chal * 64 + cf * 16 + lr;
                    const short8 bf = *(const short8*)&wfc1[(size_t)hcol * DIM + kb + kg * 8];
                    acc1[cf] = MFMA(a, bf, acc1[cf]);
                }
            }
#pragma unroll
            for (int cf = 0; cf < 4; ++cf) {
                const int hl = chal * 64 + cf * 16 + lr;
#pragma unroll
                for (int j = 0; j < 4; ++j) {
                    const int grow = r0m + (kg << 2) + j;
                    HB[grow * HBS + hl] = f2bf(gelu_exact(acc1[cf][j]));
                }
            }
        }
        __syncthreads();
        // fc2 accumulate from HB
        {
#pragma unroll 1
            for (int ks = 0; ks < 4; ++ks) {
                const int kb = ks * 32;
                const short8 a = *(const short8*)&HB[(r0m + lr) * HBS + kb + kg * 8];
#pragma unroll
                for (int ct = 0; ct < 8; ++ct) {
                    const int col = chal * 128 + ct * 16 + lr;
                    const short8 bf = *(const short8*)&wfc2[(size_t)col * FFN + ch * 128 + kb + kg * 8];
                    acc2[ct] = MFMA(a, bf, acc2[ct]);
                }
            }
        }
        __syncthreads();
    }

    // ---- Phase 5: out = x1 + mlp ----
    {
        float* ob = out + (size_t)b * (N_TOK * DIM);
#pragma unroll
        for (int ct = 0; ct < 8; ++ct) {
            const int col = chal * 128 + ct * 16 + lr;
#pragma unroll
            for (int j = 0; j < 4; ++j) {
                const int grow = r0m + (kg << 2) + j;
                ob[grow * DIM + col] = X1[grow * X1S + col] + acc2[ct][j];
            }
        }
    }
}

extern "C" void kernel_launch(void* const* d_in, const int* in_sizes, int n_in,
                              void* d_out, int out_size, void* d_ws, size_t ws_size,
                              hipStream_t stream) {
    const float* x          = (const float*)d_in[0];
    const float* qkv_w      = (const float*)d_in[1];
    const float* qkv_b      = (const float*)d_in[2];
    const float* proj_w     = (const float*)d_in[3];
    const float* proj_b     = (const float*)d_in[4];
    const float* bias_table = (const float*)d_in[5];
    const float* n1_w       = (const float*)d_in[6];
    const float* n1_b       = (const float*)d_in[7];
    const float* n2_w       = (const float*)d_in[8];
    const float* n2_b       = (const float*)d_in[9];
    const float* fc1_w      = (const float*)d_in[10];
    const float* fc1_b      = (const float*)d_in[11];
    const float* fc2_w      = (const float*)d_in[12];
    const float* fc2_b      = (const float*)d_in[13];
    const int*   rel_index  = (const int*)d_in[14];
    float* out = (float*)d_out;

    // ws layout (bytes, 16B-aligned sections)
    unsigned char* ws = (unsigned char*)d_ws;
    unsigned short* wqkv_bf = (unsigned short*)(ws);            // 768*256  u16 = 393216
    unsigned short* wfc1_bf = (unsigned short*)(ws + 393216);   // 1024*256 u16 = 524288
    unsigned short* wproj_bf= (unsigned short*)(ws + 917504);   // 256*256  u16 = 131072
    unsigned short* wfc2_bf = (unsigned short*)(ws + 1048576);  // 256*1024 u16 = 524288
    float*          bqkv    = (float*)(ws + 1572864);           // 768  f32
    float*          bfc1    = (float*)(ws + 1575936);           // 1024 f32
    float*          BT      = (float*)(ws + 1580032);           // 8*64*64 f32 (end 1711104)

    const int B = in_sizes[0] / (N_TOK * DIM);

    swin_fold<<<dim3(2432), dim3(256), 0, stream>>>(
        qkv_w, qkv_b, n1_w, n1_b, fc1_w, fc1_b, n2_w, n2_b,
        proj_w, fc2_w, bias_table, rel_index,
        wqkv_bf, bqkv, wfc1_bf, bfc1, wproj_bf, wfc2_bf, BT);

    swin_block<<<dim3(B), dim3(512), 0, stream>>>(
        x, wqkv_bf, bqkv, wproj_bf, proj_b, BT,
        wfc1_bf, bfc1, wfc2_bf, fc2_b, out);
}

// Round 8
// 851.607 us; speedup vs baseline: 2.2753x; 2.2753x over previous
//
#include <hip/hip_runtime.h>
#include <math.h>

#define N_TOK 64
#define DIM   256
#define HEADS 8
#define HDIM  32
#define FFN   1024
#define EPSV  1e-5f

// LDS strides (in elements). All give 16B-aligned rows.
#define SB    264   // bf16 [64][256] buffers (XHB / QB / KB / OB / XHB2)
#define VTS   72    // V^T bf16 [256][64]
#define PST   72    // P bf16 [64][64]
#define SSF   68    // S fp32 [64][64]
#define HBS   136   // gelu chunk bf16 [64][128]
#define X1S   260   // x1 fp32 [64][256]

typedef __attribute__((ext_vector_type(8))) short  short8;  // 8 bf16 = 4 VGPR
typedef __attribute__((ext_vector_type(4))) float  f32x4;

__device__ __forceinline__ f32x4 MFMA(short8 a, short8 b, f32x4 c) {
    return __builtin_amdgcn_mfma_f32_16x16x32_bf16(a, b, c, 0, 0, 0);
}

__device__ __forceinline__ unsigned short f2bf(float f) {
    union { float f; unsigned u; } v; v.f = f;
    unsigned r = (v.u + 0x7FFFu + ((v.u >> 16) & 1u)) >> 16;   // RNE
    return (unsigned short)r;
}

__device__ __forceinline__ short8 pack8(const float4& a, const float4& b) {
    short8 r;
    r[0] = (short)f2bf(a.x); r[1] = (short)f2bf(a.y);
    r[2] = (short)f2bf(a.z); r[3] = (short)f2bf(a.w);
    r[4] = (short)f2bf(b.x); r[5] = (short)f2bf(b.y);
    r[6] = (short)f2bf(b.z); r[7] = (short)f2bf(b.w);
    return r;
}

__device__ __forceinline__ float gelu_exact(float u) {
    return 0.5f * u * (1.0f + erff(u * 0.70710678118654752f));
}

// ---------------------------------------------------------------------------
// Fold + bf16-convert weights; pre-gather dense attention bias.
// ---------------------------------------------------------------------------
__global__ __launch_bounds__(256) void swin_fold(
    const float* __restrict__ qkv_w, const float* __restrict__ qkv_b,
    const float* __restrict__ n1_w,  const float* __restrict__ n1_b,
    const float* __restrict__ fc1_w, const float* __restrict__ fc1_b,
    const float* __restrict__ n2_w,  const float* __restrict__ n2_b,
    const float* __restrict__ proj_w, const float* __restrict__ fc2_w,
    const float* __restrict__ bias_table, const int* __restrict__ rel_index,
    unsigned short* __restrict__ wqkv_bf, float* __restrict__ bqkv,
    unsigned short* __restrict__ wfc1_bf, float* __restrict__ bfc1,
    unsigned short* __restrict__ wproj_bf, unsigned short* __restrict__ wfc2_bf,
    float* __restrict__ BT)
{
    const int blk = blockIdx.x;
    const int t   = threadIdx.x;
    __shared__ float red[4];
    if (blk < 768) {
        const int r = blk;
        const float scale = (r < DIM) ? 0.17677669529663687f : 1.0f;
        const float w = qkv_w[r * DIM + t];
        wqkv_bf[r * DIM + t] = f2bf(w * n1_w[t] * scale);
        float p = w * n1_b[t];
#pragma unroll
        for (int m = 1; m < 64; m <<= 1) p += __shfl_xor(p, m);
        if ((t & 63) == 0) red[t >> 6] = p;
        __syncthreads();
        if (t == 0) bqkv[r] = (qkv_b[r] + red[0] + red[1] + red[2] + red[3]) * scale;
    } else if (blk < 1792) {
        const int q = blk - 768;
        const float w = fc1_w[q * DIM + t];
        wfc1_bf[q * DIM + t] = f2bf(w * n2_w[t]);
        float p = w * n2_b[t];
#pragma unroll
        for (int m = 1; m < 64; m <<= 1) p += __shfl_xor(p, m);
        if ((t & 63) == 0) red[t >> 6] = p;
        __syncthreads();
        if (t == 0) bfc1[q] = fc1_b[q] + red[0] + red[1] + red[2] + red[3];
    } else if (blk < 2048) {
        const int r = blk - 1792;
        wproj_bf[r * DIM + t] = f2bf(proj_w[r * DIM + t]);
    } else if (blk < 2304) {
        const int r = blk - 2048;
#pragma unroll
        for (int i = 0; i < 4; ++i) {
            const int c = t + i * 256;
            wfc2_bf[r * FFN + c] = f2bf(fc2_w[r * FFN + c]);
        }
    } else {
        const int idx = (blk - 2304) * 256 + t;          // [0, 32768)
        const int h = idx >> 12, rc = idx & 4095;
        BT[idx] = bias_table[rel_index[rc] * HEADS + h];
    }
}

// ---------------------------------------------------------------------------
// Fused Swin block. 1 block (512 thr, 8 waves) / window.
// GEMM wave partition: each wave owns ALL 4 row-tiles x a narrow column slice
// -> every weight byte is loaded exactly once per block (was 4x redundant),
//    4x fewer global B-fragment loads; A-fragments re-read from LDS.
// Fragment layouts (v_mfma_f32_16x16x32_bf16):
//   A: lane holds A[row=l&15][k=(l>>4)*8+i], i=0..7
//   B: lane holds B[k=(l>>4)*8+i][col=l&15]
//   D: lane holds D[row=(l>>4)*4+j][col=l&15], j=0..3    (HW-verified m89)
// ---------------------------------------------------------------------------
__global__ __launch_bounds__(512, 2) void swin_block(
    const float* __restrict__ x,
    const unsigned short* __restrict__ wqkv, const float* __restrict__ bqkv,
    const unsigned short* __restrict__ wproj, const float* __restrict__ proj_b,
    const float* __restrict__ BT,
    const unsigned short* __restrict__ wfc1, const float* __restrict__ bfc1,
    const unsigned short* __restrict__ wfc2, const float* __restrict__ fc2_b,
    float* __restrict__ out)
{
    // LDS: R1 [0,33792) | R2 [33792,138240) | R3 [138240,155648)
    __shared__ __align__(16) unsigned char smem[155648];
    unsigned short* const XHB = (unsigned short*)smem;              // [64][SB] x_hat -> O -> x1_hat
    unsigned short* const QB  = (unsigned short*)(smem + 33792);    // [64][SB]
    unsigned short* const KB  = (unsigned short*)(smem + 67584);    // [64][SB]
    unsigned short* const VT  = (unsigned short*)(smem + 101376);   // [256][VTS]  (V transposed)
    float*          const X1  = (float*)(smem + 33792);             // [64][X1S], aliases QB/KB/VT
    float*          const SS  = (float*)(smem + 138240);            // [64][SSF]
    unsigned short* const PB  = (unsigned short*)(smem + 138240);   // [64][PST], aliases SS
    unsigned short* const HB  = (unsigned short*)(smem + 138240);   // [64][HBS], aliases SS

    const int b    = blockIdx.x;
    const int tid  = threadIdx.x;
    const int w    = tid >> 6;        // wave 0..7
    const int lane = tid & 63;
    const int lr   = lane & 15;       // fragment row/col
    const int kg   = lane >> 4;       // fragment k-group
    const float* __restrict__ xb = x + (size_t)b * (N_TOK * DIM);

    // ---- Phase 0: LN1 -> XHB (bf16) ----
    {
        const int r = tid >> 3, p = tid & 7;
        const int c0 = p * 32;
        float4 v[8];
        float s = 0.f, s2 = 0.f;
#pragma unroll
        for (int i = 0; i < 8; ++i) {
            v[i] = *(const float4*)(xb + r * DIM + c0 + 4 * i);
            s  += v[i].x + v[i].y + v[i].z + v[i].w;
            s2 += v[i].x * v[i].x + v[i].y * v[i].y + v[i].z * v[i].z + v[i].w * v[i].w;
        }
#pragma unroll
        for (int m = 1; m < 8; m <<= 1) { s += __shfl_xor(s, m); s2 += __shfl_xor(s2, m); }
        const float mu  = s * (1.f / 256.f);
        const float var = fmaxf(s2 * (1.f / 256.f) - mu * mu, 0.f);
        const float rs  = rsqrtf(var + EPSV);
#pragma unroll
        for (int i = 0; i < 8; i += 2) {
            float4 h0, h1;
            h0.x = (v[i].x - mu) * rs;   h0.y = (v[i].y - mu) * rs;
            h0.z = (v[i].z - mu) * rs;   h0.w = (v[i].w - mu) * rs;
            h1.x = (v[i+1].x - mu) * rs; h1.y = (v[i+1].y - mu) * rs;
            h1.z = (v[i+1].z - mu) * rs; h1.w = (v[i+1].w - mu) * rs;
            *(short8*)&XHB[r * SB + c0 + 4 * i] = pack8(h0, h1);
        }
    }
    __syncthreads();

    // ---- Phase 1: qkv GEMM (64x256 @ 256x768) -> QB, KB, VT ----
    // wave w: cols [w*96, w*96+96) (6 col-tiles) x all 4 row-tiles.
    {
        const int cw = w * 96;
        f32x4 acc[4][6];
#pragma unroll
        for (int ct = 0; ct < 6; ++ct) {
            const float bb = bqkv[cw + ct * 16 + lr];
#pragma unroll
            for (int rt = 0; rt < 4; ++rt) acc[rt][ct] = (f32x4){bb, bb, bb, bb};
        }
#pragma unroll 2
        for (int ks = 0; ks < 8; ++ks) {
            const int kb = ks * 32;
            short8 a[4];
#pragma unroll
            for (int rt = 0; rt < 4; ++rt)
                a[rt] = *(const short8*)&XHB[(rt * 16 + lr) * SB + kb + kg * 8];
#pragma unroll
            for (int ct = 0; ct < 6; ++ct) {
                const short8 bf = *(const short8*)&wqkv[(size_t)(cw + ct * 16 + lr) * DIM + kb + kg * 8];
#pragma unroll
                for (int rt = 0; rt < 4; ++rt) acc[rt][ct] = MFMA(a[rt], bf, acc[rt][ct]);
            }
        }
#pragma unroll
        for (int rt = 0; rt < 4; ++rt) {
#pragma unroll
            for (int ct = 0; ct < 6; ++ct) {
                const int o = cw + ct * 16 + lr;
#pragma unroll
                for (int j = 0; j < 4; ++j) {
                    const int grow = rt * 16 + (kg << 2) + j;
                    const unsigned short bv = f2bf(acc[rt][ct][j]);
                    if (o < 256)      QB[grow * SB + o] = bv;
                    else if (o < 512) KB[grow * SB + (o - 256)] = bv;
                    else              VT[(o - 512) * VTS + grow] = bv;
                }
            }
        }
    }
    __syncthreads();

    // ---- Phase 2: attention, per head (unchanged this round) ----
    for (int hd = 0; hd < HEADS; ++hd) {
        // [a] S = Q.K^T + bias -> SS (fp32). Wave: rows (w>>1)*16, col pair (w&1)*2.
        {
            const int rt = w >> 1, cp = w & 1;
            const short8 aq = *(const short8*)&QB[(rt * 16 + lr) * SB + hd * HDIM + kg * 8];
#pragma unroll
            for (int cc = 0; cc < 2; ++cc) {
                const int ctt = cp * 2 + cc;
                const short8 bk = *(const short8*)&KB[(ctt * 16 + lr) * SB + hd * HDIM + kg * 8];
                f32x4 sacc = (f32x4){0.f, 0.f, 0.f, 0.f};
                sacc = MFMA(aq, bk, sacc);
#pragma unroll
                for (int j = 0; j < 4; ++j) {
                    const int grow = rt * 16 + (kg << 2) + j;
                    const int gcol = ctt * 16 + lr;
                    SS[grow * SSF + gcol] = sacc[j] + BT[hd * 4096 + grow * 64 + gcol];
                }
            }
        }
        __syncthreads();
        // [b1] row softmax in registers (8 lanes per row)
        float4 f0, f1;
        {
            const int r = tid >> 3, p = tid & 7;
            const int j0 = p * 8;
            f0 = *(const float4*)&SS[r * SSF + j0];
            f1 = *(const float4*)&SS[r * SSF + j0 + 4];
            float m = fmaxf(fmaxf(fmaxf(f0.x, f0.y), fmaxf(f0.z, f0.w)),
                            fmaxf(fmaxf(f1.x, f1.y), fmaxf(f1.z, f1.w)));
#pragma unroll
            for (int msk = 1; msk < 8; msk <<= 1) m = fmaxf(m, __shfl_xor(m, msk));
            f0.x = __expf(f0.x - m); f0.y = __expf(f0.y - m);
            f0.z = __expf(f0.z - m); f0.w = __expf(f0.w - m);
            f1.x = __expf(f1.x - m); f1.y = __expf(f1.y - m);
            f1.z = __expf(f1.z - m); f1.w = __expf(f1.w - m);
            float sum = f0.x + f0.y + f0.z + f0.w + f1.x + f1.y + f1.z + f1.w;
#pragma unroll
            for (int msk = 1; msk < 8; msk <<= 1) sum += __shfl_xor(sum, msk);
            const float inv = 1.f / sum;
            f0.x *= inv; f0.y *= inv; f0.z *= inv; f0.w *= inv;
            f1.x *= inv; f1.y *= inv; f1.z *= inv; f1.w *= inv;
        }
        __syncthreads();   // all SS reads done; PB may overwrite the region
        // [b2] write probs bf16 -> PB
        {
            const int r = tid >> 3, p = tid & 7;
            *(short8*)&PB[r * PST + p * 8] = pack8(f0, f1);
        }
        __syncthreads();
        // [c] O = P @ V -> OB (=XHB) cols hd*32..  Wave: rows (w>>1)*16, col tile w&1.
        {
            const int rt = w >> 1, ctp = w & 1;
            f32x4 oacc = (f32x4){0.f, 0.f, 0.f, 0.f};
#pragma unroll
            for (int ks = 0; ks < 2; ++ks) {
                const int kb = ks * 32;
                const short8 ap = *(const short8*)&PB[(rt * 16 + lr) * PST + kb + kg * 8];
                const short8 bv = *(const short8*)&VT[(hd * HDIM + ctp * 16 + lr) * VTS + kb + kg * 8];
                oacc = MFMA(ap, bv, oacc);
            }
#pragma unroll
            for (int j = 0; j < 4; ++j) {
                const int grow = rt * 16 + (kg << 2) + j;
                XHB[grow * SB + hd * HDIM + ctp * 16 + lr] = f2bf(oacc[j]);
            }
        }
        __syncthreads();   // [c] PB/VT reads done before next [a] writes SS
    }

    // ---- Phase 3: proj + residual -> X1 (fp32, aliases QB/KB/VT) ----
    // wave w: cols [w*32, w*32+32) (2 col-tiles) x all 4 row-tiles.
    {
        const int cw = w * 32;
        f32x4 acc[4][2];
#pragma unroll
        for (int ct = 0; ct < 2; ++ct) {
            const float bb = proj_b[cw + ct * 16 + lr];
#pragma unroll
            for (int rt = 0; rt < 4; ++rt) acc[rt][ct] = (f32x4){bb, bb, bb, bb};
        }
#pragma unroll 4
        for (int ks = 0; ks < 8; ++ks) {
            const int kb = ks * 32;
            short8 a[4];
#pragma unroll
            for (int rt = 0; rt < 4; ++rt)
                a[rt] = *(const short8*)&XHB[(rt * 16 + lr) * SB + kb + kg * 8];
#pragma unroll
            for (int ct = 0; ct < 2; ++ct) {
                const short8 bf = *(const short8*)&wproj[(size_t)(cw + ct * 16 + lr) * DIM + kb + kg * 8];
#pragma unroll
                for (int rt = 0; rt < 4; ++rt) acc[rt][ct] = MFMA(a[rt], bf, acc[rt][ct]);
            }
        }
#pragma unroll
        for (int rt = 0; rt < 4; ++rt) {
#pragma unroll
            for (int ct = 0; ct < 2; ++ct) {
                const int col = cw + ct * 16 + lr;
#pragma unroll
                for (int j = 0; j < 4; ++j) {
                    const int grow = rt * 16 + (kg << 2) + j;
                    X1[grow * X1S + col] = acc[rt][ct][j] + xb[grow * DIM + col];
                }
            }
        }
    }
    __syncthreads();

    // ---- LN2: X1 -> XHB (x1_hat bf16; O dead) ----
    {
        const int r = tid >> 3, p = tid & 7;
        const int c0 = p * 32;
        float4 v[8];
        float s = 0.f, s2 = 0.f;
#pragma unroll
        for (int i = 0; i < 8; ++i) {
            v[i] = *(const float4*)&X1[r * X1S + c0 + 4 * i];
            s  += v[i].x + v[i].y + v[i].z + v[i].w;
            s2 += v[i].x * v[i].x + v[i].y * v[i].y + v[i].z * v[i].z + v[i].w * v[i].w;
        }
#pragma unroll
        for (int m = 1; m < 8; m <<= 1) { s += __shfl_xor(s, m); s2 += __shfl_xor(s2, m); }
        const float mu  = s * (1.f / 256.f);
        const float var = fmaxf(s2 * (1.f / 256.f) - mu * mu, 0.f);
        const float rs  = rsqrtf(var + EPSV);
#pragma unroll
        for (int i = 0; i < 8; i += 2) {
            float4 h0, h1;
            h0.x = (v[i].x - mu) * rs;   h0.y = (v[i].y - mu) * rs;
            h0.z = (v[i].z - mu) * rs;   h0.w = (v[i].w - mu) * rs;
            h1.x = (v[i+1].x - mu) * rs; h1.y = (v[i+1].y - mu) * rs;
            h1.z = (v[i+1].z - mu) * rs; h1.w = (v[i+1].w - mu) * rs;
            *(short8*)&XHB[r * SB + c0 + 4 * i] = pack8(h0, h1);
        }
    }
    __syncthreads();

    // ---- Phase 4: MLP, hidden in 8 chunks of 128 through HB ----
    // fc1: wave w -> 16 hidden cols/chunk; fc2: wave w -> 32 out cols.
    const int cw2 = w * 32;
    f32x4 acc2[4][2];
#pragma unroll
    for (int ct = 0; ct < 2; ++ct) {
        const float bb = fc2_b[cw2 + ct * 16 + lr];
#pragma unroll
        for (int rt = 0; rt < 4; ++rt) acc2[rt][ct] = (f32x4){bb, bb, bb, bb};
    }
    for (int ch = 0; ch < 8; ++ch) {
        // fc1 chunk + gelu -> HB
        {
            const int hw = w * 16;                    // within-chunk hidden offset
            const int hcol = ch * 128 + hw + lr;      // global hidden index
            f32x4 acc1[4];
            {
                const float bb = bfc1[hcol];
#pragma unroll
                for (int rt = 0; rt < 4; ++rt) acc1[rt] = (f32x4){bb, bb, bb, bb};
            }
#pragma unroll 4
            for (int ks = 0; ks < 8; ++ks) {
                const int kb = ks * 32;
                short8 a[4];
#pragma unroll
                for (int rt = 0; rt < 4; ++rt)
                    a[rt] = *(const short8*)&XHB[(rt * 16 + lr) * SB + kb + kg * 8];
                const short8 bf = *(const short8*)&wfc1[(size_t)hcol * DIM + kb + kg * 8];
#pragma unroll
                for (int rt = 0; rt < 4; ++rt) acc1[rt] = MFMA(a[rt], bf, acc1[rt]);
            }
#pragma unroll
            for (int rt = 0; rt < 4; ++rt) {
#pragma unroll
                for (int j = 0; j < 4; ++j) {
                    const int grow = rt * 16 + (kg << 2) + j;
                    HB[grow * HBS + hw + lr] = f2bf(gelu_exact(acc1[rt][j]));
                }
            }
        }
        __syncthreads();
        // fc2 accumulate from HB
        {
#pragma unroll
            for (int ks = 0; ks < 4; ++ks) {
                const int kb = ks * 32;
                short8 a[4];
#pragma unroll
                for (int rt = 0; rt < 4; ++rt)
                    a[rt] = *(const short8*)&HB[(rt * 16 + lr) * HBS + kb + kg * 8];
#pragma unroll
                for (int ct = 0; ct < 2; ++ct) {
                    const short8 bf = *(const short8*)&wfc2[(size_t)(cw2 + ct * 16 + lr) * FFN + ch * 128 + kb + kg * 8];
#pragma unroll
                    for (int rt = 0; rt < 4; ++rt) acc2[rt][ct] = MFMA(a[rt], bf, acc2[rt][ct]);
                }
            }
        }
        __syncthreads();
    }

    // ---- Phase 5: out = x1 + mlp ----
    {
        float* ob = out + (size_t)b * (N_TOK * DIM);
#pragma unroll
        for (int rt = 0; rt < 4; ++rt) {
#pragma unroll
            for (int ct = 0; ct < 2; ++ct) {
                const int col = cw2 + ct * 16 + lr;
#pragma unroll
                for (int j = 0; j < 4; ++j) {
                    const int grow = rt * 16 + (kg << 2) + j;
                    ob[grow * DIM + col] = X1[grow * X1S + col] + acc2[rt][ct][j];
                }
            }
        }
    }
}

extern "C" void kernel_launch(void* const* d_in, const int* in_sizes, int n_in,
                              void* d_out, int out_size, void* d_ws, size_t ws_size,
                              hipStream_t stream) {
    const float* x          = (const float*)d_in[0];
    const float* qkv_w      = (const float*)d_in[1];
    const float* qkv_b      = (const float*)d_in[2];
    const float* proj_w     = (const float*)d_in[3];
    const float* proj_b     = (const float*)d_in[4];
    const float* bias_table = (const float*)d_in[5];
    const float* n1_w       = (const float*)d_in[6];
    const float* n1_b       = (const float*)d_in[7];
    const float* n2_w       = (const float*)d_in[8];
    const float* n2_b       = (const float*)d_in[9];
    const float* fc1_w      = (const float*)d_in[10];
    const float* fc1_b      = (const float*)d_in[11];
    const float* fc2_w      = (const float*)d_in[12];
    const float* fc2_b      = (const float*)d_in[13];
    const int*   rel_index  = (const int*)d_in[14];
    float* out = (float*)d_out;

    // ws layout (bytes, 16B-aligned sections)
    unsigned char* ws = (unsigned char*)d_ws;
    unsigned short* wqkv_bf = (unsigned short*)(ws);            // 768*256  u16 = 393216
    unsigned short* wfc1_bf = (unsigned short*)(ws + 393216);   // 1024*256 u16 = 524288
    unsigned short* wproj_bf= (unsigned short*)(ws + 917504);   // 256*256  u16 = 131072
    unsigned short* wfc2_bf = (unsigned short*)(ws + 1048576);  // 256*1024 u16 = 524288
    float*          bqkv    = (float*)(ws + 1572864);           // 768  f32
    float*          bfc1    = (float*)(ws + 1575936);           // 1024 f32
    float*          BT      = (float*)(ws + 1580032);           // 8*64*64 f32 (end 1711104)

    const int B = in_sizes[0] / (N_TOK * DIM);

    swin_fold<<<dim3(2432), dim3(256), 0, stream>>>(
        qkv_w, qkv_b, n1_w, n1_b, fc1_w, fc1_b, n2_w, n2_b,
        proj_w, fc2_w, bias_table, rel_index,
        wqkv_bf, bqkv, wfc1_bf, bfc1, wproj_bf, wfc2_bf, BT);

    swin_block<<<dim3(B), dim3(512), 0, stream>>>(
        x, wqkv_bf, bqkv, wproj_bf, proj_b, BT,
        wfc1_bf, bfc1, wfc2_bf, fc2_b, out);
}